// Round 2
// baseline (138.885 us; speedup 1.0000x reference)
//
#include <hip/hip_runtime.h>
#include <math.h>

// Problem constants
#define NCLS   100
#define BATCH_ 2048
#define OK     9        // POLICY_NUMS + 2
#define FHALF  64       // FEATURE_NUMS / 2
#define NPOLB  4        // policy blocks (256 pair-rows each)
#define NLOGB  512      // logits blocks (4 rows each, 1 wave/row)
#define NBLK   (NPOLB + NLOGB)

// Workspace layout (floats). ws[0] (4 bytes) = ticket counter (memset to 0).
// All other slots are unconditionally written by their owning block.
#define LP_OFF 16                    // logits partials: 512 x {ce, kl}
#define PS_OFF (LP_OFF + NLOGB * 2)  // policy stats: 4 x 72
#define PB_OFF (PS_OFF + NPOLB * 72) // policy buckets: 4 x 320

__device__ __forceinline__ float waveSum(float v) {
#pragma unroll
    for (int off = 32; off; off >>= 1) v += __shfl_xor(v, off, 64);
    return v;
}
__device__ __forceinline__ float waveMax(float v) {
#pragma unroll
    for (int off = 32; off; off >>= 1) v = fmaxf(v, __shfl_xor(v, off, 64));
    return v;
}

__global__ __launch_bounds__(256) void fused_kernel(
        const float* __restrict__ slog, const float* __restrict__ tlog,
        const float* __restrict__ spol, const float* __restrict__ tpol,
        const float* __restrict__ W1,   const float* __restrict__ bias1,
        const float* __restrict__ W2,   const float* __restrict__ bias2,
        const int*   __restrict__ tgt,  float* __restrict__ ws,
        unsigned int* __restrict__ cnt, float* __restrict__ out)
{
    __shared__ float w1s[OK * 128];
    __shared__ float w2s[OK * 128];
    __shared__ float bktL[320];
    __shared__ float statsW[4][72];
    __shared__ float redL[8];
    __shared__ unsigned int ticket_s;
    // combine-phase LDS (disjoint from the above; safe either path)
    __shared__ float statsC[72];
    __shared__ float bktC[320];
    __shared__ float cekl[8];

    const int tid  = threadIdx.x;
    const int wave = tid >> 6;
    const int lane = tid & 63;

    if (blockIdx.x < NPOLB) {
        // ---------------- policy: pair-linear closed-form stats ----------------
        const int pb = blockIdx.x;
        for (int idx = tid; idx < OK * 128; idx += 256) { w1s[idx] = W1[idx]; w2s[idx] = W2[idx]; }
        for (int idx = tid; idx < 320; idx += 256) bktL[idx] = 0.f;
        __syncthreads();

        const int i = pb * 256 + tid;                      // pair-row 0..1023
        const float4* f1s = (const float4*)(spol + (2 * i) * FHALF);
        const float4* f2s = (const float4*)(spol + (2 * i + 1) * FHALF);
        const float4* f1t = (const float4*)(tpol + (2 * i) * FHALF);
        const float4* f2t = (const float4*)(tpol + (2 * i + 1) * FHALF);

        float As[OK], Bs[OK], At[OK], Bt[OK];
#pragma unroll
        for (int k = 0; k < OK; ++k) { As[k] = 0.f; Bs[k] = 0.f; At[k] = 0.f; Bt[k] = 0.f; }
        for (int f4 = 0; f4 < FHALF / 4; ++f4) {
            float4 a4 = f1s[f4], b4 = f2s[f4], c4 = f1t[f4], d4 = f2t[f4];
            const float* ap = (const float*)&a4;
            const float* bp = (const float*)&b4;
            const float* cp = (const float*)&c4;
            const float* dp = (const float*)&d4;
#pragma unroll
            for (int j = 0; j < 4; ++j) {
                const int f = f4 * 4 + j;
                const float av = ap[j], bv = bp[j], cv = cp[j], dv = dp[j];
#pragma unroll
                for (int k = 0; k < OK; ++k) {
                    As[k] = fmaf(av, w2s[k * 128 + f],      As[k]);
                    Bs[k] = fmaf(bv, w2s[k * 128 + 64 + f], Bs[k]);
                    At[k] = fmaf(cv, w1s[k * 128 + f],      At[k]);
                    Bt[k] = fmaf(dv, w1s[k * 128 + 64 + f], Bt[k]);
                }
            }
        }

#pragma unroll
        for (int k = 0; k < OK; ++k) {
            float du = Bs[k] - Bt[k], dw = As[k] - At[k];
            float v0 = waveSum(du),     v1 = waveSum(du * du);
            float v2 = waveSum(dw),     v3 = waveSum(dw * dw);
            float v4 = waveSum(Bs[k]),  v5 = waveSum(Bs[k] * Bs[k]);
            float v6 = waveSum(As[k]),  v7 = waveSum(As[k] * As[k]);
            if (lane == 0) {
                float* p = &statsW[wave][k * 8];
                p[0] = v0; p[1] = v1; p[2] = v2; p[3] = v3;
                p[4] = v4; p[5] = v5; p[6] = v6; p[7] = v7;
            }
        }

        const int* t1r = tgt + (2 * i) * 8;
        const int* t2r = tgt + (2 * i + 1) * 8;
#pragma unroll
        for (int c0 = 0; c0 < 8; ++c0) {
            int v1i = t1r[c0], v2i = t2r[c0];
            atomicAdd(&bktL[0 * 80 + c0 * 10 + v1i], 1.0f);
            atomicAdd(&bktL[1 * 80 + c0 * 10 + v2i], 1.0f);
            atomicAdd(&bktL[2 * 80 + c0 * 10 + v1i], As[c0 + 1]);
            atomicAdd(&bktL[3 * 80 + c0 * 10 + v2i], Bs[c0 + 1]);
        }
        __syncthreads();
        if (tid < 72)
            ws[PS_OFF + pb * 72 + tid] =
                statsW[0][tid] + statsW[1][tid] + statsW[2][tid] + statsW[3][tid];
        for (int idx = tid; idx < 320; idx += 256)
            ws[PB_OFF + pb * 320 + idx] = bktL[idx];
    } else {
        // ---------------- logits: CE + KL(T=4), one wave per row ----------------
        const int r = (blockIdx.x - NPOLB) * 4 + wave;     // 0..2047
        const float* x = slog + r * NCLS;
        const float* y = tlog + r * NCLS;
        const int label = tgt[r * 8];                      // issue early (indirect chain)
        const bool has2 = lane < (NCLS - 64);
        float x1 = x[lane];
        float y1 = y[lane];
        float x2 = has2 ? x[lane + 64] : -3.0e38f;
        float y2 = has2 ? y[lane + 64] : -3.0e38f;
        float xl = x[label];
        float mx = waveMax(fmaxf(x1, x2));
        float my = waveMax(fmaxf(y1, y2));
        float se1  = waveSum(expf(x1 - mx) + (has2 ? expf(x2 - mx) : 0.f));
        float se4s = waveSum(expf((x1 - mx) * 0.25f) + (has2 ? expf((x2 - mx) * 0.25f) : 0.f));
        float e1 = expf((y1 - my) * 0.25f);
        float e2 = has2 ? expf((y2 - my) * 0.25f) : 0.f;
        float se4t = waveSum(e1 + e2);
        float tnum = waveSum(e1 * (y1 - x1) * 0.25f + (has2 ? e2 * (y2 - x2) * 0.25f : 0.f));
        if (lane == 0) {
            float logZ1  = mx + logf(se1);
            float logZ4s = mx * 0.25f + logf(se4s);
            float logZ4t = my * 0.25f + logf(se4t);
            redL[wave * 2]     = logZ1 - xl;                          // ce row term
            redL[wave * 2 + 1] = tnum / se4t + logZ4s - logZ4t;       // kl row term
        }
        __syncthreads();
        if (tid == 0) {
            const int blk = blockIdx.x - NPOLB;
            ws[LP_OFF + blk * 2]     = redL[0] + redL[2] + redL[4] + redL[6];
            ws[LP_OFF + blk * 2 + 1] = redL[1] + redL[3] + redL[5] + redL[7];
        }
    }

    // ---------------- last-block combine (ticket) ----------------
    __threadfence();                       // release: make partial slots visible
    if (tid == 0) ticket_s = atomicAdd(cnt, 1u);
    __syncthreads();
    if (ticket_s != NBLK - 1) return;
    __threadfence();                       // acquire: invalidate stale cache lines

    float ce = 0.f, kl = 0.f;
    for (int s = tid; s < NLOGB; s += 256) {
        ce += ws[LP_OFF + s * 2];
        kl += ws[LP_OFF + s * 2 + 1];
    }
    ce = waveSum(ce); kl = waveSum(kl);
    if (lane == 0) { cekl[wave * 2] = ce; cekl[wave * 2 + 1] = kl; }
    if (tid < 72)
        statsC[tid] = ws[PS_OFF + tid] + ws[PS_OFF + 72 + tid]
                    + ws[PS_OFF + 144 + tid] + ws[PS_OFF + 216 + tid];
    for (int idx = tid; idx < 320; idx += 256)
        bktC[idx] = ws[PB_OFF + idx] + ws[PB_OFF + 320 + idx]
                  + ws[PB_OFF + 640 + idx] + ws[PB_OFF + 960 + idx];
    __syncthreads();

    if (tid == 0) {
        const double N = 1024.0, M = 1048576.0;
        double ce_main = (double)(cekl[0] + cekl[2] + cekl[4] + cekl[6]) / (double)BATCH_;
        double kl_main = (double)(cekl[1] + cekl[3] + cekl[5] + cekl[7]) * 16.0
                       / (double)(BATCH_ * NCLS);

        double kl_pol = 0.0, Sp_acc = 0.0;
        double SumL[OK], SumL2[OK];
        for (int k = 0; k < OK; ++k) {
            const float* p = &statsC[k * 8];
            double D1u = p[0], D2u = p[1], D1w = p[2], D2w = p[3];
            double U1 = p[4], U2 = p[5], Wa1 = p[6], Wa2 = p[7];
            double cd = (double)bias2[k] - (double)bias1[k];
            double b  = (double)bias2[k];
            double S = N * D2u + N * (D2w + 2.0 * cd * D1w + N * cd * cd)
                     + 2.0 * D1u * (D1w + N * cd);
            if (k == 0)      kl_pol += S / M;
            else if (k == 1) kl_pol += 0.5 * S / M;
            else             Sp_acc += S;
            SumL[k]  = N * U1 + N * Wa1 + M * b;
            SumL2[k] = N * U2 + N * (Wa2 + 2.0 * b * Wa1 + N * b * b)
                     + 2.0 * U1 * (Wa1 + N * b);
        }
        kl_pol += 0.001 * Sp_acc / (7.0 * M);

        double ce_I = -((double)statsC[4] + (double)statsC[6] + N * (double)bias2[0]) / M;

        const float* cnt1 = &bktC[0];
        const float* cnt2 = &bktC[80];
        const float* sA   = &bktC[160];
        const float* sB   = &bktC[240];
        double ce_C = 0.0, ceP = 0.0;
        for (int c0 = 0; c0 < 8; ++c0) {
            double ms = 0.0, pc = 0.0;
            for (int v = 0; v < 10; ++v) {
                double c1 = (double)cnt1[c0 * 10 + v], c2 = (double)cnt2[c0 * 10 + v];
                ms += c1 * (double)sB[c0 * 10 + v] + c2 * (double)sA[c0 * 10 + v];
                pc += c1 * c2;
            }
            ms += (double)bias2[c0 + 1] * pc;
            if (c0 == 0) {
                ce_C = -0.5 * ms / M;
            } else {
                int k = c0 + 1;
                double sg = 2.0 * ms - SumL[k];
                ceP += SumL2[k] - 2.0 * sg + M;
            }
        }
        ceP *= 0.001 / (7.0 * M);

        out[0] = (float)(ce_main + kl_main + kl_pol + ce_I + ce_C + ceP);
    }
}

extern "C" void kernel_launch(void* const* d_in, const int* in_sizes, int n_in,
                              void* d_out, int out_size, void* d_ws, size_t ws_size,
                              hipStream_t stream) {
    const float* slog = (const float*)d_in[0];
    const float* tlog = (const float*)d_in[1];
    const float* spol = (const float*)d_in[2];
    const float* tpol = (const float*)d_in[3];
    const float* W1   = (const float*)d_in[4];
    const float* b1   = (const float*)d_in[5];
    const float* W2   = (const float*)d_in[6];
    const float* b2   = (const float*)d_in[7];
    const int*   tgt  = (const int*)d_in[8];
    float* ws = (float*)d_ws;
    unsigned int* cnt = (unsigned int*)d_ws;   // ws[0]

    hipMemsetAsync(d_ws, 0, 4, stream);        // zero the ticket counter only
    fused_kernel<<<NBLK, 256, 0, stream>>>(slog, tlog, spol, tpol,
                                           W1, b1, W2, b2, tgt, ws, cnt,
                                           (float*)d_out);
}

// Round 3
// 98.066 us; speedup vs baseline: 1.4162x; 1.4162x over previous
//
#include <hip/hip_runtime.h>
#include <math.h>

// Problem constants
#define NCLS   100
#define BATCH_ 2048
#define OK     9        // POLICY_NUMS + 2
#define FHALF  64       // FEATURE_NUMS / 2

#define NLOGB  128      // logits blocks: 1024 thr = 16 waves, 1 row/wave
#define NPOLB  16       // policy blocks: wave 0 handles 64 pair-rows
#define NBLK   (NLOGB + NPOLB)

// Workspace layout (floats). Every slot below is written exactly once by its
// owning block in K1 (plain stores, no atomics, no fences); K2 reduces.
#define LP_OFF 0                        // 128 x {ce, kl}
#define PS_OFF (LP_OFF + NLOGB * 2)     // 16 x 72 policy stats
#define PB_OFF (PS_OFF + NPOLB * 72)    // 16 x 320 policy buckets

__device__ __forceinline__ float waveSum(float v) {
#pragma unroll
    for (int off = 32; off; off >>= 1) v += __shfl_xor(v, off, 64);
    return v;
}
__device__ __forceinline__ float waveMax(float v) {
#pragma unroll
    for (int off = 32; off; off >>= 1) v = fmaxf(v, __shfl_xor(v, off, 64));
    return v;
}

__global__ __launch_bounds__(1024) void stats_kernel(
        const float* __restrict__ slog, const float* __restrict__ tlog,
        const float* __restrict__ spol, const float* __restrict__ tpol,
        const float* __restrict__ W1,   const float* __restrict__ W2,
        const int*   __restrict__ tgt,  float* __restrict__ ws)
{
    __shared__ float w1s[OK * 128];
    __shared__ float w2s[OK * 128];
    __shared__ float bkt[320];
    __shared__ float redL[32];

    const int tid  = threadIdx.x;
    const int wave = tid >> 6;
    const int lane = tid & 63;

    if (blockIdx.x < NLOGB) {
        // ---------- logits: CE + KL(T=4), one wave per row, 16 rows/block ----------
        const int r = blockIdx.x * 16 + wave;              // 0..2047
        const float* x = slog + r * NCLS;
        const float* y = tlog + r * NCLS;
        const int label = tgt[r * 8];                      // start indirect chain early
        const bool has2 = lane < (NCLS - 64);
        float x1 = x[lane];
        float y1 = y[lane];
        float x2 = has2 ? x[lane + 64] : -3.0e38f;
        float y2 = has2 ? y[lane + 64] : -3.0e38f;
        float xl = x[label];
        float mx = waveMax(fmaxf(x1, x2));
        float my = waveMax(fmaxf(y1, y2));
        float se1  = waveSum(expf(x1 - mx) + (has2 ? expf(x2 - mx) : 0.f));
        float se4s = waveSum(expf((x1 - mx) * 0.25f) + (has2 ? expf((x2 - mx) * 0.25f) : 0.f));
        float e1 = expf((y1 - my) * 0.25f);
        float e2 = has2 ? expf((y2 - my) * 0.25f) : 0.f;
        float se4t = waveSum(e1 + e2);
        float tnum = waveSum(e1 * (y1 - x1) * 0.25f + (has2 ? e2 * (y2 - x2) * 0.25f : 0.f));
        if (lane == 0) {
            float logZ1  = mx + logf(se1);
            float logZ4s = mx * 0.25f + logf(se4s);
            float logZ4t = my * 0.25f + logf(se4t);
            redL[wave * 2]     = logZ1 - xl;
            redL[wave * 2 + 1] = tnum / se4t + logZ4s - logZ4t;
        }
        __syncthreads();
        if (tid < 2) {
            float s = 0.f;
#pragma unroll
            for (int w = 0; w < 16; ++w) s += redL[w * 2 + tid];
            ws[LP_OFF + blockIdx.x * 2 + tid] = s;
        }
    } else {
        // ---------- policy: pair-linear closed-form stats (wave 0 only) ----------
        const int pb = blockIdx.x - NLOGB;                 // 0..15
        for (int idx = tid; idx < OK * 128; idx += 1024) { w1s[idx] = W1[idx]; w2s[idx] = W2[idx]; }
        if (tid < 320) bkt[tid] = 0.f;
        __syncthreads();

        float As[OK], Bs[OK];
        if (tid < 64) {
            const int i = pb * 64 + tid;                   // pair-row 0..1023
            const float4* f1s = (const float4*)(spol + (2 * i) * FHALF);
            const float4* f2s = (const float4*)(spol + (2 * i + 1) * FHALF);
            const float4* f1t = (const float4*)(tpol + (2 * i) * FHALF);
            const float4* f2t = (const float4*)(tpol + (2 * i + 1) * FHALF);

            float At[OK], Bt[OK];
#pragma unroll
            for (int k = 0; k < OK; ++k) { As[k] = 0.f; Bs[k] = 0.f; At[k] = 0.f; Bt[k] = 0.f; }
            for (int f4 = 0; f4 < FHALF / 4; ++f4) {
                float4 a4 = f1s[f4], b4 = f2s[f4], c4 = f1t[f4], d4 = f2t[f4];
                const float* ap = (const float*)&a4;
                const float* bp = (const float*)&b4;
                const float* cp = (const float*)&c4;
                const float* dp = (const float*)&d4;
#pragma unroll
                for (int j = 0; j < 4; ++j) {
                    const int f = f4 * 4 + j;
                    const float av = ap[j], bv = bp[j], cv = cp[j], dv = dp[j];
#pragma unroll
                    for (int k = 0; k < OK; ++k) {
                        As[k] = fmaf(av, w2s[k * 128 + f],      As[k]);
                        Bs[k] = fmaf(bv, w2s[k * 128 + 64 + f], Bs[k]);
                        At[k] = fmaf(cv, w1s[k * 128 + f],      At[k]);
                        Bt[k] = fmaf(dv, w1s[k * 128 + 64 + f], Bt[k]);
                    }
                }
            }

#pragma unroll
            for (int k = 0; k < OK; ++k) {
                float du = Bs[k] - Bt[k], dw = As[k] - At[k];
                float v0 = waveSum(du),     v1 = waveSum(du * du);
                float v2 = waveSum(dw),     v3 = waveSum(dw * dw);
                float v4 = waveSum(Bs[k]),  v5 = waveSum(Bs[k] * Bs[k]);
                float v6 = waveSum(As[k]),  v7 = waveSum(As[k] * As[k]);
                if (lane == 0) {
                    float* p = ws + PS_OFF + pb * 72 + k * 8;
                    p[0] = v0; p[1] = v1; p[2] = v2; p[3] = v3;
                    p[4] = v4; p[5] = v5; p[6] = v6; p[7] = v7;
                }
            }

            const int* t1r = tgt + (2 * i) * 8;
            const int* t2r = tgt + (2 * i + 1) * 8;
#pragma unroll
            for (int c0 = 0; c0 < 8; ++c0) {
                int v1i = t1r[c0], v2i = t2r[c0];
                atomicAdd(&bkt[0 * 80 + c0 * 10 + v1i], 1.0f);
                atomicAdd(&bkt[1 * 80 + c0 * 10 + v2i], 1.0f);
                atomicAdd(&bkt[2 * 80 + c0 * 10 + v1i], As[c0 + 1]);
                atomicAdd(&bkt[3 * 80 + c0 * 10 + v2i], Bs[c0 + 1]);
            }
        }
        __syncthreads();
        if (tid < 320) ws[PB_OFF + pb * 320 + tid] = bkt[tid];
    }
}

__global__ __launch_bounds__(256) void combine_kernel(
        const float* __restrict__ ws,
        const float* __restrict__ bias1, const float* __restrict__ bias2,
        float* __restrict__ out)
{
    __shared__ float statsC[72];
    __shared__ float bktC[320];
    __shared__ float cekl[8];

    const int tid  = threadIdx.x;
    const int wave = tid >> 6;
    const int lane = tid & 63;

    float ce = 0.f, kl = 0.f;
    if (tid < NLOGB) {
        ce = ws[LP_OFF + tid * 2];
        kl = ws[LP_OFF + tid * 2 + 1];
    }
    ce = waveSum(ce); kl = waveSum(kl);
    if (lane == 0) { cekl[wave * 2] = ce; cekl[wave * 2 + 1] = kl; }

    if (tid < 72) {
        float s = 0.f;
#pragma unroll
        for (int b = 0; b < NPOLB; ++b) s += ws[PS_OFF + b * 72 + tid];
        statsC[tid] = s;
    }
    for (int idx = tid; idx < 320; idx += 256) {
        float s = 0.f;
#pragma unroll
        for (int b = 0; b < NPOLB; ++b) s += ws[PB_OFF + b * 320 + idx];
        bktC[idx] = s;
    }
    __syncthreads();

    if (tid == 0) {
        const double N = 1024.0, M = 1048576.0;
        double ce_main = (double)(cekl[0] + cekl[2] + cekl[4] + cekl[6]) / (double)BATCH_;
        double kl_main = (double)(cekl[1] + cekl[3] + cekl[5] + cekl[7]) * 16.0
                       / (double)(BATCH_ * NCLS);

        double kl_pol = 0.0, Sp_acc = 0.0;
        double SumL[OK], SumL2[OK];
        for (int k = 0; k < OK; ++k) {
            const float* p = &statsC[k * 8];
            double D1u = p[0], D2u = p[1], D1w = p[2], D2w = p[3];
            double U1 = p[4], U2 = p[5], Wa1 = p[6], Wa2 = p[7];
            double cd = (double)bias2[k] - (double)bias1[k];
            double b  = (double)bias2[k];
            double S = N * D2u + N * (D2w + 2.0 * cd * D1w + N * cd * cd)
                     + 2.0 * D1u * (D1w + N * cd);
            if (k == 0)      kl_pol += S / M;
            else if (k == 1) kl_pol += 0.5 * S / M;
            else             Sp_acc += S;
            SumL[k]  = N * U1 + N * Wa1 + M * b;
            SumL2[k] = N * U2 + N * (Wa2 + 2.0 * b * Wa1 + N * b * b)
                     + 2.0 * U1 * (Wa1 + N * b);
        }
        kl_pol += 0.001 * Sp_acc / (7.0 * M);

        double ce_I = -((double)statsC[4] + (double)statsC[6] + N * (double)bias2[0]) / M;

        const float* cnt1 = &bktC[0];
        const float* cnt2 = &bktC[80];
        const float* sA   = &bktC[160];
        const float* sB   = &bktC[240];
        double ce_C = 0.0, ceP = 0.0;
        for (int c0 = 0; c0 < 8; ++c0) {
            double ms = 0.0, pc = 0.0;
            for (int v = 0; v < 10; ++v) {
                double c1 = (double)cnt1[c0 * 10 + v], c2 = (double)cnt2[c0 * 10 + v];
                ms += c1 * (double)sB[c0 * 10 + v] + c2 * (double)sA[c0 * 10 + v];
                pc += c1 * c2;
            }
            ms += (double)bias2[c0 + 1] * pc;
            if (c0 == 0) {
                ce_C = -0.5 * ms / M;
            } else {
                int k = c0 + 1;
                double sg = 2.0 * ms - SumL[k];
                ceP += SumL2[k] - 2.0 * sg + M;
            }
        }
        ceP *= 0.001 / (7.0 * M);

        out[0] = (float)(ce_main + kl_main + kl_pol + ce_I + ce_C + ceP);
    }
}

extern "C" void kernel_launch(void* const* d_in, const int* in_sizes, int n_in,
                              void* d_out, int out_size, void* d_ws, size_t ws_size,
                              hipStream_t stream) {
    const float* slog = (const float*)d_in[0];
    const float* tlog = (const float*)d_in[1];
    const float* spol = (const float*)d_in[2];
    const float* tpol = (const float*)d_in[3];
    const float* W1   = (const float*)d_in[4];
    const float* b1   = (const float*)d_in[5];
    const float* W2   = (const float*)d_in[6];
    const float* b2   = (const float*)d_in[7];
    const int*   tgt  = (const int*)d_in[8];
    float* ws = (float*)d_ws;

    stats_kernel<<<NBLK, 1024, 0, stream>>>(slog, tlog, spol, tpol, W1, W2, tgt, ws);
    combine_kernel<<<1, 256, 0, stream>>>(ws, b1, b2, (float*)d_out);
}